// Round 7
// baseline (169.685 us; speedup 1.0000x reference)
//
#include <hip/hip_runtime.h>

typedef unsigned int   u32;
typedef unsigned long long u64;

#define BATCH   8
#define NDATA   8192
#define NPOINT  1024
#define NSAMPLE 32
#define CFEAT   64
#define ROWF    67          // 3 xyz + 64 feat

// f32-element offsets of the concatenated outputs
#define OUT_IDX (BATCH*NPOINT*NSAMPLE*ROWF)              // 17563648
#define OUT_GX  (OUT_IDX + BATCH*NPOINT*NSAMPLE)         // 17825792

// f32 -> bf16 (RNE) -> f32: match the harness's bf16-rounded np reference
__device__ __forceinline__ float rnbf(float f) {
    u32 b = __float_as_uint(f);
    b += 0x7FFFu + ((b >> 16) & 1u);
    return __uint_as_float(b & 0xFFFF0000u);
}
__device__ __forceinline__ int clampidx(int v) {
    return (v < 0) ? 0 : (v > NDATA-1 ? NDATA-1 : v);
}

// one wave per query; 4 queries per block (all same batch since 1024 % 4 == 0)
__global__ __launch_bounds__(256)
void grouping_kernel(const float* __restrict__ new_xyz,
                     const float* __restrict__ xyz,
                     const float* __restrict__ points,
                     float* __restrict__ out)
{
    __shared__ float wd[4][NSAMPLE];    // sorted ascending (dist, idx) lex
    __shared__ int   wi[4][NSAMPLE];
    __shared__ int   sel[4][NSAMPLE];

    const int tid  = threadIdx.x;
    const int wv   = tid >> 6;
    const int lane = tid & 63;
    const int q    = blockIdx.x * 4 + wv;    // global query id, < 8192
    const int b    = q >> 10;                // batch (NPOINT = 1024)

    const float qx = new_xyz[q*3 + 0];
    const float qy = new_xyz[q*3 + 1];
    const float qz = new_xyz[q*3 + 2];
    const float* bx = xyz + (size_t)b * NDATA * 3;   // 96 KB/batch, L2-resident

    int wn = 0;                               // wave-uniform: min(#in-radius, 32)
    float mind = 3.402823466e38f; int mini = 0;

    for (int k = 0; k < NDATA/64; ++k) {
        int i = (k << 6) + lane;
        float x = bx[i*3 + 0];
        float y = bx[i*3 + 1];
        float z = bx[i*3 + 2];
        // exact np f32 semantics: no FMA, left-to-right sum, f32 sqrt
        float dx = __fsub_rn(x, qx), dy = __fsub_rn(y, qy), dz = __fsub_rn(z, qz);
        float d2 = __fadd_rn(__fadd_rn(__fmul_rn(dx,dx), __fmul_rn(dy,dy)),
                             __fmul_rn(dz,dz));
        float s  = __fsqrt_rn(d2);
        if (s < mind) { mind = s; mini = i; }   // per-lane (dist, lowest idx)

        u64 m = __ballot(s < 0.2f);
        while (m) {                              // serial, wave-uniform insertion
            int j = __builtin_ctzll(m);
            m &= m - 1;
            float dj = __shfl(s, j);
            int   ij = (k << 6) + j;             // strictly increasing insert order
            if (lane == 0) {
                bool take = (wn < NSAMPLE) ? true : (dj < wd[wv][NSAMPLE-1]);
                if (take) {
                    int pos = (wn < NSAMPLE) ? wn : NSAMPLE-1;
                    while (pos > 0 && wd[wv][pos-1] > dj) {  // equals stay before (stable)
                        wd[wv][pos] = wd[wv][pos-1];
                        wi[wv][pos] = wi[wv][pos-1];
                        --pos;
                    }
                    wd[wv][pos] = dj;
                    wi[wv][pos] = ij;
                }
            }
            wn = (wn < NSAMPLE) ? wn + 1 : NSAMPLE;
        }
    }

    // cross-lane argmin reduce (dist, lowest index) for empty-ball padding
    for (int off = 32; off; off >>= 1) {
        float od = __shfl_xor(mind, off);
        int   oi = __shfl_xor(mini, off);
        if (od < mind || (od == mind && oi < mini)) { mind = od; mini = oi; }
    }
    if (lane == 0) {
        int pad = (wn > 0) ? wi[wv][0] : mini;   // sorted_idx[0]
        for (int r = 0; r < NSAMPLE; ++r)
            sel[wv][r] = clampidx((r < wn) ? wi[wv][r] : pad);
    }
    __syncthreads();   // uniform barrier: publish sel to all lanes

    // ---- outputs: f32 stores, values pre-rounded through bf16 ----
    // idx  (chunk 1)
    if (lane < NSAMPLE)
        out[OUT_IDX + (size_t)q*NSAMPLE + lane] = rnbf((float)sel[wv][lane]);

    // grouped_xyz (chunk 2) + the xyz columns of new_points (chunk 0)
    for (int e = lane; e < NSAMPLE*3; e += 64) {
        int sR = e / 3, c = e - sR*3;
        int is = sel[wv][sR];
        float v = rnbf(bx[is*3 + c]);
        out[OUT_GX + (size_t)q*(NSAMPLE*3) + e] = v;
        out[(size_t)q*(NSAMPLE*ROWF) + sR*ROWF + c] = v;
    }

    // new_points feature columns: 32 rows x 64 feats, 256B contiguous per row
    const float* prow = points + (size_t)b * NDATA * CFEAT;
    float* onp = out + (size_t)q * (NSAMPLE*ROWF);
    for (int r = 0; r < NSAMPLE; ++r) {
        int is = sel[wv][r];
        onp[r*ROWF + 3 + lane] = rnbf(prow[(size_t)is * CFEAT + lane]);
    }
}

extern "C" void kernel_launch(void* const* d_in, const int* in_sizes, int n_in,
                              void* d_out, int out_size, void* d_ws, size_t ws_size,
                              hipStream_t stream) {
    grouping_kernel<<<(BATCH*NPOINT)/4, 256, 0, stream>>>(
        (const float*)d_in[0],   // new_xyz (f32)
        (const float*)d_in[1],   // xyz     (f32)
        (const float*)d_in[2],   // points  (f32)
        (float*)d_out);
}